// Round 1
// 399.293 us; speedup vs baseline: 1.0575x; 1.0575x over previous
//
#include <hip/hip_runtime.h>
#include <math.h>

#define CC   256
#define HW   4096
#define OC3  384
#define HID  128
#define DH   32
#define NM   4
#define NPART 8
#define SCALE 0.17677669529663688f  // 32^-0.5

typedef __bf16 bf16x8 __attribute__((ext_vector_type(8)));
typedef float  f32x4  __attribute__((ext_vector_type(4)));

__device__ __forceinline__ ushort f2bf(float x) {
    union { float f; unsigned u; } v; v.f = x;
    unsigned r = v.u + 0x7fffu + ((v.u >> 16) & 1u);   // RNE
    return (ushort)(r >> 16);
}
__device__ __forceinline__ float bf2f(ushort b) {
    union { unsigned u; float f; } v; v.u = ((unsigned)b) << 16; return v.f;
}
__device__ __forceinline__ void g2l16(const void* g, void* l) {
    __builtin_amdgcn_global_load_lds(
        (const __attribute__((address_space(1))) void*)g,
        (__attribute__((address_space(3))) void*)l, 16, 0, 0);
}

// ---------------- prep: wq2t[o][c] = wqkv[o][c]*g1[c]*16 (bf16); woutt = bf16(wout)
__global__ void k_prep(const float* __restrict__ wqkv, const float* __restrict__ g1,
                       const float* __restrict__ wout,
                       ushort* __restrict__ wq2t, ushort* __restrict__ woutt) {
    int o = blockIdx.x, t = threadIdx.x;
    wq2t[(size_t)o * CC + t] = f2bf(wqkv[(size_t)o * CC + t] * g1[t] * 16.0f);
    if (o < CC && t < HID) woutt[(size_t)o * HID + t] = f2bf(wout[(size_t)o * HID + t]);
}

// ---------------- fused rms-norm + transpose + bf16: xnT[b][pix][c]
__global__ __launch_bounds__(256) void k_xn(const float* __restrict__ x,
                                            ushort* __restrict__ xnT) {
    __shared__ float xt[256 * 33];
    __shared__ float ps[8 * 33];
    __shared__ float invn[32];
    int tid = threadIdx.x;
    int pix0 = blockIdx.x * 32;
    int b = pix0 >> 12, hw0 = pix0 & 4095;
    int p = tid & 31, cg = tid >> 5;
    const float* xb = x + (size_t)b * CC * HW + hw0;
    #pragma unroll 4
    for (int step = 0; step < 32; ++step) {
        int c = step * 8 + cg;
        xt[c * 33 + p] = xb[(size_t)c * HW + p];
    }
    __syncthreads();
    float s = 0.f;
    #pragma unroll 8
    for (int i = 0; i < 32; ++i) { float v = xt[(cg * 32 + i) * 33 + p]; s += v * v; }
    ps[cg * 33 + p] = s;
    __syncthreads();
    if (tid < 32) {
        float t = 0.f;
        #pragma unroll
        for (int g = 0; g < 8; ++g) t += ps[g * 33 + tid];
        invn[tid] = 1.0f / fmaxf(sqrtf(t), 1e-12f);
    }
    __syncthreads();
    float inv = invn[p];
    ushort* dst = xnT + ((size_t)(pix0 + p)) * CC + cg * 32;
    #pragma unroll
    for (int q = 0; q < 4; ++q) {
        uint4 pk; ushort* o8 = (ushort*)&pk;
        #pragma unroll
        for (int i = 0; i < 8; ++i) o8[i] = f2bf(xt[(cg * 32 + q * 8 + i) * 33 + p] * inv);
        *(uint4*)&dst[q * 8] = pk;
    }
}

// ---------------- qkv MFMA GEMM: 128oc x 128pix tiles, BK=32, bf16 out
// XCD-bijective swizzle: the 3 m-blocks sharing one B(pix,b) tile get
// consecutive logical ids inside one XCD's contiguous chunk -> B fetched
// once from HBM, siblings hit that XCD's L2. nwg=3072, 3072%8==0.
__global__ __launch_bounds__(256) void k_qkv(const ushort* __restrict__ wq2t,
        const ushort* __restrict__ xnT, ushort* __restrict__ qkv) {
    __shared__ ushort As[128 * 32];
    __shared__ ushort Bs[128 * 32];
    int tid = threadIdx.x;
    int lin = blockIdx.x + 3 * (blockIdx.y + 32 * blockIdx.z);   // 0..3071
    int swz = (lin & 7) * 384 + (lin >> 3);                      // bijective
    int m0 = (swz % 3) * 128;
    int t_ = swz / 3;                                            // 0..1023
    int p0 = (t_ & 31) * 128;
    int b  = t_ >> 5;
    int lane = tid & 63, wid = tid >> 6;
    int l15 = tid & 15, quad = (tid >> 4) & 3;
    int wm = wid >> 1, wn = wid & 1;
    int rsub = lane >> 2, csub = (lane & 3) * 8;
    const ushort* Ab = wq2t + (size_t)m0 * CC;
    const ushort* Bb = xnT + ((size_t)(b * HW + p0)) * CC;
    f32x4 acc[4][4];
    #pragma unroll
    for (int i = 0; i < 4; ++i)
        #pragma unroll
        for (int j = 0; j < 4; ++j) acc[i][j] = (f32x4){0.f, 0.f, 0.f, 0.f};
    for (int k0 = 0; k0 < CC; k0 += 32) {
        __syncthreads();
        #pragma unroll
        for (int q = 0; q < 2; ++q) {
            int rw = wid * 32 + q * 16;
            g2l16(Ab + (size_t)(rw + rsub) * CC + k0 + csub, &As[rw * 32]);
            g2l16(Bb + (size_t)(rw + rsub) * CC + k0 + csub, &Bs[rw * 32]);
        }
        __syncthreads();
        bf16x8 af[4], bfr[4];
        #pragma unroll
        for (int mt = 0; mt < 4; ++mt)
            af[mt] = *(const bf16x8*)&As[(wm * 64 + mt * 16 + l15) * 32 + quad * 8];
        #pragma unroll
        for (int nt = 0; nt < 4; ++nt)
            bfr[nt] = *(const bf16x8*)&Bs[(wn * 64 + nt * 16 + l15) * 32 + quad * 8];
        #pragma unroll
        for (int mt = 0; mt < 4; ++mt)
            #pragma unroll
            for (int nt = 0; nt < 4; ++nt)
                acc[mt][nt] = __builtin_amdgcn_mfma_f32_16x16x32_bf16(
                                  af[mt], bfr[nt], acc[mt][nt], 0, 0, 0);
    }
    #pragma unroll
    for (int mt = 0; mt < 4; ++mt) {
        int o = m0 + wm * 64 + mt * 16 + quad * 4;
        #pragma unroll
        for (int nt = 0; nt < 4; ++nt) {
            int pix = p0 + wn * 64 + nt * 16 + l15;
            ushort* dst = qkv + ((size_t)(b * OC3 + o)) * HW + pix;
            #pragma unroll
            for (int r = 0; r < 4; ++r) dst[(size_t)r * HW] = f2bf(acc[mt][nt][r]);
        }
    }
}

// ---------------- k-softmax stats over bf16 k rows
__global__ void k_ksoft(const ushort* __restrict__ qkv, const float* __restrict__ memkv,
                        float* __restrict__ kmaxb, float* __restrict__ rsumb) {
    int row = blockIdx.x * 4 + (threadIdx.x >> 6);
    int lane = threadIdx.x & 63;
    int b = row >> 7, hd = row & 127;
    const ushort* kp = qkv + ((size_t)(b * OC3 + HID + hd)) * HW;
    float m = -1e30f;
    for (int i = lane; i < HW; i += 64) m = fmaxf(m, bf2f(kp[i]));
    #pragma unroll
    for (int s = 1; s < 64; s <<= 1) m = fmaxf(m, __shfl_xor(m, s));
    const float* mk = memkv + hd * NM;
    #pragma unroll
    for (int j = 0; j < NM; ++j) m = fmaxf(m, mk[j]);
    float s = 0.f;
    for (int i = lane; i < HW; i += 64) s += __expf(bf2f(kp[i]) - m);
    #pragma unroll
    for (int t = 1; t < 64; t <<= 1) s += __shfl_xor(s, t);
    #pragma unroll
    for (int j = 0; j < NM; ++j) s += __expf(mk[j] - m);
    if (lane == 0) { kmaxb[row] = m; rsumb[row] = 1.0f / s; }
}

// ---------------- context partials: ctxp[part][bh][d*32+e], n split 8 ways
__global__ __launch_bounds__(256) void k_ctx(const ushort* __restrict__ qkv,
        const float* __restrict__ memkv, const float* __restrict__ kmaxb,
        const float* __restrict__ rsumb, float* __restrict__ ctxp) {
    __shared__ float kl[DH][65];
    __shared__ float vl[DH][65];
    __shared__ float red[256 * 33];
    int tid = threadIdx.x;
    int bh = blockIdx.x;            // 0..127
    int part = blockIdx.y;          // 0..7
    int b = bh >> 2, h = bh & 3;
    const ushort* kp = qkv + ((size_t)(b * OC3 + HID + h * DH)) * HW + part * 512;
    const ushort* vp = qkv + ((size_t)(b * OC3 + 2 * HID + h * DH)) * HW + part * 512;
    int slot = tid & 31, nng = tid >> 5;
    int d0 = (slot >> 2) * 4, e0 = (slot & 3) * 8;
    int rowbase = bh * DH;
    float acc[4][8];
    #pragma unroll
    for (int i = 0; i < 4; ++i)
        #pragma unroll
        for (int j = 0; j < 8; ++j) acc[i][j] = 0.f;
    for (int n0 = 0; n0 < 512; n0 += 64) {
        __syncthreads();
        #pragma unroll
        for (int q = 0; q < 8; ++q) {
            int idx = tid + q * 256;
            int r = idx >> 6, nn = idx & 63;
            float kraw = bf2f(kp[(size_t)r * HW + n0 + nn]);
            kl[r][nn] = __expf(kraw - kmaxb[rowbase + r]) * rsumb[rowbase + r];
            vl[r][nn] = bf2f(vp[(size_t)r * HW + n0 + nn]);
        }
        __syncthreads();
        #pragma unroll 2
        for (int t = 0; t < 8; ++t) {
            int nn = nng * 8 + t;
            float kv[4], vv[8];
            #pragma unroll
            for (int i = 0; i < 4; ++i) kv[i] = kl[d0 + i][nn];
            #pragma unroll
            for (int j = 0; j < 8; ++j) vv[j] = vl[e0 + j][nn];
            #pragma unroll
            for (int i = 0; i < 4; ++i)
                #pragma unroll
                for (int j = 0; j < 8; ++j) acc[i][j] += kv[i] * vv[j];
        }
    }
    __syncthreads();
    #pragma unroll
    for (int i = 0; i < 4; ++i)
        #pragma unroll
        for (int j = 0; j < 8; ++j) red[tid * 33 + i * 8 + j] = acc[i][j];
    __syncthreads();
    #pragma unroll
    for (int q = 0; q < 4; ++q) {
        int o = tid * 4 + q;
        int d = o >> 5, e = o & 31;
        int sl = (d >> 2) * 4 + (e >> 3);
        int k = (d & 3) * 8 + (e & 7);
        float s = 0.f;
        #pragma unroll
        for (int g = 0; g < 8; ++g) s += red[(g * 32 + sl) * 33 + k];
        if (part == 0) {   // memory-kv contribution added once
            float km = kmaxb[rowbase + d], rsm = rsumb[rowbase + d];
            #pragma unroll
            for (int m = 0; m < NM; ++m) {
                float kw = __expf(memkv[(h * DH + d) * NM + m] - km) * rsm;
                s += kw * memkv[512 + (h * DH + e) * NM + m];
            }
        }
        ctxp[(size_t)part * 131072 + (size_t)bh * 1024 + o] = s;
    }
}

// ---------------- fold ctx into out-proj weight, once per batch:
// W2[b][oc][h*32+d] = sum_e wout[oc][h*32+e] * ctx_b[h][d][e]   (bf16)
// This removes stage-3 MFMA + outT transpose + per-block ctxp summation
// from the hot final kernel (was done 64x per batch, now 1x).
__global__ __launch_bounds__(256) void k_w2(const float* __restrict__ ctxp,
        const ushort* __restrict__ woutt, ushort* __restrict__ W2) {
    __shared__ ushort ctxb[4 * 32 * 40];   // [h][d][e], pad 40 (80B rows, 16B-aligned)
    int tid = threadIdx.x, b = blockIdx.x;
    int wid = tid >> 6;
    int l15 = tid & 15, quad = (tid >> 4) & 3;
    // sum the 8 n-partials -> bf16 LDS (mem-kv already folded in at part 0)
    #pragma unroll
    for (int j = 0; j < 16; ++j) {
        int idx = tid + j * 256;            // 0..4095 = h*1024 + d*32 + e
        float s = 0.f;
        #pragma unroll
        for (int p = 0; p < NPART; ++p)
            s += ctxp[(size_t)p * 131072 + (size_t)b * 4096 + idx];
        int h = idx >> 10, d = (idx >> 5) & 31, e = idx & 31;
        ctxb[(h * 32 + d) * 40 + e] = f2bf(s);
    }
    __syncthreads();
    // per wave: 64 oc rows; per head: one K=32 MFMA step (M=64, N=32)
    #pragma unroll
    for (int h = 0; h < 4; ++h) {
        f32x4 acc[4][2];
        #pragma unroll
        for (int i = 0; i < 4; ++i)
            #pragma unroll
            for (int j = 0; j < 2; ++j) acc[i][j] = (f32x4){0.f, 0.f, 0.f, 0.f};
        bf16x8 af[4], bfr[2];
        #pragma unroll
        for (int mt = 0; mt < 4; ++mt)
            af[mt] = *(const bf16x8*)&woutt[(size_t)(wid * 64 + mt * 16 + l15) * HID
                                            + h * DH + quad * 8];
        #pragma unroll
        for (int nt = 0; nt < 2; ++nt)
            bfr[nt] = *(const bf16x8*)&ctxb[(h * 32 + nt * 16 + l15) * 40 + quad * 8];
        #pragma unroll
        for (int mt = 0; mt < 4; ++mt)
            #pragma unroll
            for (int nt = 0; nt < 2; ++nt)
                acc[mt][nt] = __builtin_amdgcn_mfma_f32_16x16x32_bf16(
                                  af[mt], bfr[nt], acc[mt][nt], 0, 0, 0);
        #pragma unroll
        for (int mt = 0; mt < 4; ++mt)
            #pragma unroll
            for (int nt = 0; nt < 2; ++nt)
                #pragma unroll
                for (int r = 0; r < 4; ++r) {
                    int oc = wid * 64 + mt * 16 + quad * 4 + r;
                    int d  = nt * 16 + l15;
                    W2[((size_t)b * CC + oc) * HID + h * DH + d] = f2bf(acc[mt][nt][r]);
                }
    }
}

// ---------------- final: q-softmax + single GEMM (W2_b @ softq) + bias + rms*g2
__global__ __launch_bounds__(256) void k_final(const ushort* __restrict__ qkv,
        const ushort* __restrict__ W2, const float* __restrict__ bout,
        const float* __restrict__ g2, float* __restrict__ y) {
    __shared__ __align__(16) ushort sq[64 * 136];   // [pix][hid] softmaxed q, bf16
    __shared__ __align__(16) ushort Ws[256 * 32];   // staged W2 K-tile
    __shared__ float red[64 * 17];
    __shared__ float invs[64];
    __shared__ float bl[256];
    __shared__ float gl[256];
    int tid = threadIdx.x;
    int b = blockIdx.y;
    int hwb = blockIdx.x * 64;
    int lane = tid & 63, wid = tid >> 6;
    int l15 = tid & 15, quad = (tid >> 4) & 3;
    bl[tid] = bout[tid];
    gl[tid] = g2[tid];

    // ---- softmax over d per (h=wid, pix=lane); write sq[pix][hid] bf16
    {
        const ushort* qp = qkv + ((size_t)b * OC3 + wid * DH) * HW + hwb + lane;
        float vd[32];
        float m = -1e30f;
        #pragma unroll
        for (int d = 0; d < 32; ++d) {
            float v = bf2f(qp[(size_t)d * HW]);   // 64 lanes contiguous per row
            vd[d] = v; m = fmaxf(m, v);
        }
        float s = 0.f;
        #pragma unroll
        for (int d = 0; d < 32; ++d) { float e = __expf(vd[d] - m); vd[d] = e; s += e; }
        float r_ = SCALE / s;
        #pragma unroll
        for (int q8 = 0; q8 < 4; ++q8) {
            uint4 pk; ushort* o8 = (ushort*)&pk;
            #pragma unroll
            for (int i = 0; i < 8; ++i) o8[i] = f2bf(vd[q8 * 8 + i] * r_);
            *(uint4*)&sq[lane * 136 + wid * DH + q8 * 8] = pk;
        }
    }

    // ---- GEMM: y0[256 oc][64 pix] = W2_b[256][128] @ sq^T, K=128 in 4 steps
    f32x4 acc[4][4];
    #pragma unroll
    for (int i = 0; i < 4; ++i)
        #pragma unroll
        for (int j = 0; j < 4; ++j) acc[i][j] = (f32x4){0.f, 0.f, 0.f, 0.f};
    int rsub = lane >> 2, csub = (lane & 3) * 8;
    const ushort* W2b = W2 + (size_t)b * CC * HID;
    for (int k0 = 0; k0 < HID; k0 += 32) {
        __syncthreads();    // 1st iter: also guards sq writes
        #pragma unroll
        for (int q = 0; q < 4; ++q) {
            int rw = wid * 64 + q * 16;
            g2l16(W2b + (size_t)(rw + rsub) * HID + k0 + csub, &Ws[rw * 32]);
        }
        __syncthreads();
        bf16x8 af[4], bfr[4];
        #pragma unroll
        for (int mt = 0; mt < 4; ++mt)
            af[mt] = *(const bf16x8*)&Ws[(wid * 64 + mt * 16 + l15) * 32 + quad * 8];
        #pragma unroll
        for (int nt = 0; nt < 4; ++nt)
            bfr[nt] = *(const bf16x8*)&sq[(nt * 16 + l15) * 136 + k0 + quad * 8];
        #pragma unroll
        for (int mt = 0; mt < 4; ++mt)
            #pragma unroll
            for (int nt = 0; nt < 4; ++nt)
                acc[mt][nt] = __builtin_amdgcn_mfma_f32_16x16x32_bf16(
                                  af[mt], bfr[nt], acc[mt][nt], 0, 0, 0);
    }

    // ---- epilogue: bias, rms-norm over 256 oc, *g2*16
    float part[4] = {0.f, 0.f, 0.f, 0.f};
    #pragma unroll
    for (int mt = 0; mt < 4; ++mt)
        #pragma unroll
        for (int r = 0; r < 4; ++r) {
            int oc = wid * 64 + mt * 16 + quad * 4 + r;
            float bo = bl[oc];
            #pragma unroll
            for (int nt = 0; nt < 4; ++nt) {
                float v = acc[mt][nt][r] + bo;
                acc[mt][nt][r] = v;
                part[nt] += v * v;
            }
        }
    __syncthreads();
    #pragma unroll
    for (int nt = 0; nt < 4; ++nt)
        red[(nt * 16 + l15) * 17 + wid * 4 + quad] = part[nt];
    __syncthreads();
    if (tid < 64) {
        float s = 0.f;
        #pragma unroll
        for (int g = 0; g < 16; ++g) s += red[tid * 17 + g];
        invs[tid] = 1.0f / fmaxf(sqrtf(s), 1e-12f);
    }
    __syncthreads();
    #pragma unroll
    for (int mt = 0; mt < 4; ++mt)
        #pragma unroll
        for (int nt = 0; nt < 4; ++nt) {
            int pix = nt * 16 + l15;
            float iv = invs[pix];
            #pragma unroll
            for (int r = 0; r < 4; ++r) {
                int oc = wid * 64 + mt * 16 + quad * 4 + r;
                y[((size_t)(b * CC + oc)) * HW + hwb + pix] = acc[mt][nt][r] * iv * gl[oc] * 16.0f;
            }
        }
}

extern "C" void kernel_launch(void* const* d_in, const int* in_sizes, int n_in,
                              void* d_out, int out_size, void* d_ws, size_t ws_size,
                              hipStream_t stream) {
    const float* x     = (const float*)d_in[0];
    const float* g1    = (const float*)d_in[1];
    const float* memkv = (const float*)d_in[2];
    const float* wqkv  = (const float*)d_in[3];
    const float* wout  = (const float*)d_in[4];
    const float* bout  = (const float*)d_in[5];
    const float* g2    = (const float*)d_in[6];
    float* y = (float*)d_out;

    char* w = (char*)d_ws;
    ushort* wq2t  = (ushort*)w;  w += (size_t)OC3 * CC * 2;
    ushort* woutt = (ushort*)w;  w += (size_t)CC * HID * 2;
    float*  kmaxb = (float*)w;   w += 4096 * 4;
    float*  rsumb = (float*)w;   w += 4096 * 4;
    float*  ctxp  = (float*)w;   w += (size_t)NPART * 131072 * 4;  // 4 MB
    ushort* W2    = (ushort*)w;  w += (size_t)32 * CC * HID * 2;   // 2 MB
    ushort* xnT   = (ushort*)w;  w += (size_t)32 * HW * CC * 2;    // 67 MB
    ushort* qkv   = (ushort*)w;  w += (size_t)32 * OC3 * HW * 2;   // 100 MB

    k_prep  <<<dim3(384),       dim3(256), 0, stream>>>(wqkv, g1, wout, wq2t, woutt);
    k_xn    <<<dim3(4096),      dim3(256), 0, stream>>>(x, xnT);
    k_qkv   <<<dim3(3, 32, 32), dim3(256), 0, stream>>>(wq2t, xnT, qkv);
    k_ksoft <<<dim3(1024),      dim3(256), 0, stream>>>(qkv, memkv, kmaxb, rsumb);
    k_ctx   <<<dim3(128, 8),    dim3(256), 0, stream>>>(qkv, memkv, kmaxb, rsumb, ctxp);
    k_w2    <<<dim3(32),        dim3(256), 0, stream>>>(ctxp, woutt, W2);
    k_final <<<dim3(64, 32),    dim3(256), 0, stream>>>(qkv, W2, bout, g2, y);
}

// Round 3
// 368.856 us; speedup vs baseline: 1.1447x; 1.0825x over previous
//
#include <hip/hip_runtime.h>
#include <math.h>

#define CC   256
#define HW   4096
#define OC3  384
#define HID  128
#define DH   32
#define NM   4
#define NPART 8
#define SCALE 0.17677669529663688f  // 32^-0.5

typedef __bf16 bf16x8 __attribute__((ext_vector_type(8)));
typedef float  f32x4  __attribute__((ext_vector_type(4)));

__device__ __forceinline__ ushort f2bf(float x) {
    union { float f; unsigned u; } v; v.f = x;
    unsigned r = v.u + 0x7fffu + ((v.u >> 16) & 1u);   // RNE
    return (ushort)(r >> 16);
}
__device__ __forceinline__ float bf2f(ushort b) {
    union { unsigned u; float f; } v; v.u = ((unsigned)b) << 16; return v.f;
}
__device__ __forceinline__ void g2l16(const void* g, void* l) {
    __builtin_amdgcn_global_load_lds(
        (const __attribute__((address_space(1))) void*)g,
        (__attribute__((address_space(3))) void*)l, 16, 0, 0);
}

// ---------------- prep: wq2t[o][c] = wqkv[o][c]*g1[c]*16 (bf16); woutt = bf16(wout)
__global__ void k_prep(const float* __restrict__ wqkv, const float* __restrict__ g1,
                       const float* __restrict__ wout,
                       ushort* __restrict__ wq2t, ushort* __restrict__ woutt) {
    int o = blockIdx.x, t = threadIdx.x;
    wq2t[(size_t)o * CC + t] = f2bf(wqkv[(size_t)o * CC + t] * g1[t] * 16.0f);
    if (o < CC && t < HID) woutt[(size_t)o * HID + t] = f2bf(wout[(size_t)o * HID + t]);
}

// ---------------- fused rms-norm + transpose + bf16: xnT[b][pix][c]
// v2: float4 global loads (was scalar; latency-bound at 1.7 TB/s / 33% occ).
// LDS stride 36 floats: b128 writes and b32 column reads both conflict-free.
__global__ __launch_bounds__(256) void k_xn(const float* __restrict__ x,
                                            ushort* __restrict__ xnT) {
    __shared__ float xt[256 * 36];
    __shared__ float ps[8 * 33];
    __shared__ float invn[32];
    int tid = threadIdx.x;
    int pix0 = blockIdx.x * 32;
    int b = pix0 >> 12, hw0 = pix0 & 4095;
    int p = tid & 31, cg = tid >> 5;
    const float* xb = x + (size_t)b * CC * HW + hw0;
    {
        int cr = tid >> 3;          // 0..31: row within pass
        int chunk = tid & 7;        // 0..7: 4-pixel chunk
        #pragma unroll
        for (int pass = 0; pass < 8; ++pass) {
            int c = pass * 32 + cr;
            float4 v = *(const float4*)&xb[(size_t)c * HW + chunk * 4];
            *(float4*)&xt[c * 36 + chunk * 4] = v;
        }
    }
    __syncthreads();
    float s = 0.f;
    #pragma unroll 8
    for (int i = 0; i < 32; ++i) { float v = xt[(cg * 32 + i) * 36 + p]; s += v * v; }
    ps[cg * 33 + p] = s;
    __syncthreads();
    if (tid < 32) {
        float t = 0.f;
        #pragma unroll
        for (int g = 0; g < 8; ++g) t += ps[g * 33 + tid];
        invn[tid] = 1.0f / fmaxf(sqrtf(t), 1e-12f);
    }
    __syncthreads();
    float inv = invn[p];
    ushort* dst = xnT + ((size_t)(pix0 + p)) * CC + cg * 32;
    #pragma unroll
    for (int q = 0; q < 4; ++q) {
        uint4 pk; ushort* o8 = (ushort*)&pk;
        #pragma unroll
        for (int i = 0; i < 8; ++i) o8[i] = f2bf(xt[(cg * 32 + q * 8 + i) * 36 + p] * inv);
        *(uint4*)&dst[q * 8] = pk;
    }
}

// ---------------- qkv MFMA GEMM: 128oc x 128pix tiles, BK=32, bf16 out
// XCD-bijective swizzle: the 3 m-blocks sharing one B(pix,b) tile get
// consecutive logical ids inside one XCD's contiguous chunk -> B fetched
// once from HBM, siblings hit that XCD's L2. nwg=3072, 3072%8==0.
__global__ __launch_bounds__(256) void k_qkv(const ushort* __restrict__ wq2t,
        const ushort* __restrict__ xnT, ushort* __restrict__ qkv) {
    __shared__ ushort As[128 * 32];
    __shared__ ushort Bs[128 * 32];
    int tid = threadIdx.x;
    int lin = blockIdx.x + 3 * (blockIdx.y + 32 * blockIdx.z);   // 0..3071
    int swz = (lin & 7) * 384 + (lin >> 3);                      // bijective
    int m0 = (swz % 3) * 128;
    int t_ = swz / 3;                                            // 0..1023
    int p0 = (t_ & 31) * 128;
    int b  = t_ >> 5;
    int lane = tid & 63, wid = tid >> 6;
    int l15 = tid & 15, quad = (tid >> 4) & 3;
    int wm = wid >> 1, wn = wid & 1;
    int rsub = lane >> 2, csub = (lane & 3) * 8;
    const ushort* Ab = wq2t + (size_t)m0 * CC;
    const ushort* Bb = xnT + ((size_t)(b * HW + p0)) * CC;
    f32x4 acc[4][4];
    #pragma unroll
    for (int i = 0; i < 4; ++i)
        #pragma unroll
        for (int j = 0; j < 4; ++j) acc[i][j] = (f32x4){0.f, 0.f, 0.f, 0.f};
    for (int k0 = 0; k0 < CC; k0 += 32) {
        __syncthreads();
        #pragma unroll
        for (int q = 0; q < 2; ++q) {
            int rw = wid * 32 + q * 16;
            g2l16(Ab + (size_t)(rw + rsub) * CC + k0 + csub, &As[rw * 32]);
            g2l16(Bb + (size_t)(rw + rsub) * CC + k0 + csub, &Bs[rw * 32]);
        }
        __syncthreads();
        bf16x8 af[4], bfr[4];
        #pragma unroll
        for (int mt = 0; mt < 4; ++mt)
            af[mt] = *(const bf16x8*)&As[(wm * 64 + mt * 16 + l15) * 32 + quad * 8];
        #pragma unroll
        for (int nt = 0; nt < 4; ++nt)
            bfr[nt] = *(const bf16x8*)&Bs[(wn * 64 + nt * 16 + l15) * 32 + quad * 8];
        #pragma unroll
        for (int mt = 0; mt < 4; ++mt)
            #pragma unroll
            for (int nt = 0; nt < 4; ++nt)
                acc[mt][nt] = __builtin_amdgcn_mfma_f32_16x16x32_bf16(
                                  af[mt], bfr[nt], acc[mt][nt], 0, 0, 0);
    }
    #pragma unroll
    for (int mt = 0; mt < 4; ++mt) {
        int o = m0 + wm * 64 + mt * 16 + quad * 4;
        #pragma unroll
        for (int nt = 0; nt < 4; ++nt) {
            int pix = p0 + wn * 64 + nt * 16 + l15;
            ushort* dst = qkv + ((size_t)(b * OC3 + o)) * HW + pix;
            #pragma unroll
            for (int r = 0; r < 4; ++r) dst[(size_t)r * HW] = f2bf(acc[mt][nt][r]);
        }
    }
}

// ---------------- k-softmax stats over bf16 k rows (v2: uint4 loads)
__global__ void k_ksoft(const ushort* __restrict__ qkv, const float* __restrict__ memkv,
                        float* __restrict__ kmaxb, float* __restrict__ rsumb) {
    int row = blockIdx.x * 4 + (threadIdx.x >> 6);
    int lane = threadIdx.x & 63;
    int b = row >> 7, hd = row & 127;
    const ushort* kp = qkv + ((size_t)(b * OC3 + HID + hd)) * HW;
    float m = -1e30f;
    #pragma unroll
    for (int i0 = 0; i0 < HW; i0 += 512) {
        uint4 pk = *(const uint4*)&kp[i0 + lane * 8];
        const ushort* e = (const ushort*)&pk;
        #pragma unroll
        for (int j = 0; j < 8; ++j) m = fmaxf(m, bf2f(e[j]));
    }
    #pragma unroll
    for (int s = 1; s < 64; s <<= 1) m = fmaxf(m, __shfl_xor(m, s));
    const float* mk = memkv + hd * NM;
    #pragma unroll
    for (int j = 0; j < NM; ++j) m = fmaxf(m, mk[j]);
    float s = 0.f;
    #pragma unroll
    for (int i0 = 0; i0 < HW; i0 += 512) {
        uint4 pk = *(const uint4*)&kp[i0 + lane * 8];
        const ushort* e = (const ushort*)&pk;
        #pragma unroll
        for (int j = 0; j < 8; ++j) s += __expf(bf2f(e[j]) - m);
    }
    #pragma unroll
    for (int t = 1; t < 64; t <<= 1) s += __shfl_xor(s, t);
    #pragma unroll
    for (int j = 0; j < NM; ++j) s += __expf(mk[j] - m);
    if (lane == 0) { kmaxb[row] = m; rsumb[row] = 1.0f / s; }
}

// ---------------- context partials: ctxp[part][bh][d*32+e], n split 8 ways
// v2: uint4 k/v loads; per-row kmax/rsum hoisted out of the n-loop.
__global__ __launch_bounds__(256) void k_ctx(const ushort* __restrict__ qkv,
        const float* __restrict__ memkv, const float* __restrict__ kmaxb,
        const float* __restrict__ rsumb, float* __restrict__ ctxp) {
    __shared__ float kl[DH][65];
    __shared__ float vl[DH][65];
    __shared__ float red[256 * 33];
    int tid = threadIdx.x;
    int bh = blockIdx.x;            // 0..127
    int part = blockIdx.y;          // 0..7
    int b = bh >> 2, h = bh & 3;
    int lr = tid >> 3;              // 0..31: k/v row this thread stages
    int nn8 = (tid & 7) * 8;        // 8-col chunk
    const ushort* kp = qkv + ((size_t)(b * OC3 + HID + h * DH) + lr) * HW + part * 512 + nn8;
    const ushort* vp = qkv + ((size_t)(b * OC3 + 2 * HID + h * DH) + lr) * HW + part * 512 + nn8;
    int rowbase = bh * DH;
    float kmr = kmaxb[rowbase + lr], rsr = rsumb[rowbase + lr];
    int slot = tid & 31, nng = tid >> 5;
    int d0 = (slot >> 2) * 4, e0 = (slot & 3) * 8;
    float acc[4][8];
    #pragma unroll
    for (int i = 0; i < 4; ++i)
        #pragma unroll
        for (int j = 0; j < 8; ++j) acc[i][j] = 0.f;
    for (int n0 = 0; n0 < 512; n0 += 64) {
        __syncthreads();
        uint4 kv4 = *(const uint4*)&kp[n0];
        uint4 vv4 = *(const uint4*)&vp[n0];
        const ushort* ke = (const ushort*)&kv4;
        const ushort* ve = (const ushort*)&vv4;
        #pragma unroll
        for (int j = 0; j < 8; ++j) {
            kl[lr][nn8 + j] = __expf(bf2f(ke[j]) - kmr) * rsr;
            vl[lr][nn8 + j] = bf2f(ve[j]);
        }
        __syncthreads();
        #pragma unroll 2
        for (int t = 0; t < 8; ++t) {
            int nn = nng * 8 + t;
            float kv[4], vv[8];
            #pragma unroll
            for (int i = 0; i < 4; ++i) kv[i] = kl[d0 + i][nn];
            #pragma unroll
            for (int j = 0; j < 8; ++j) vv[j] = vl[e0 + j][nn];
            #pragma unroll
            for (int i = 0; i < 4; ++i)
                #pragma unroll
                for (int j = 0; j < 8; ++j) acc[i][j] += kv[i] * vv[j];
        }
    }
    __syncthreads();
    #pragma unroll
    for (int i = 0; i < 4; ++i)
        #pragma unroll
        for (int j = 0; j < 8; ++j) red[tid * 33 + i * 8 + j] = acc[i][j];
    __syncthreads();
    #pragma unroll
    for (int q = 0; q < 4; ++q) {
        int o = tid * 4 + q;
        int d = o >> 5, e = o & 31;
        int sl = (d >> 2) * 4 + (e >> 3);
        int k = (d & 3) * 8 + (e & 7);
        float s = 0.f;
        #pragma unroll
        for (int g = 0; g < 8; ++g) s += red[(g * 32 + sl) * 33 + k];
        if (part == 0) {   // memory-kv contribution added once
            float km = kmaxb[rowbase + d], rsm = rsumb[rowbase + d];
            #pragma unroll
            for (int m = 0; m < NM; ++m) {
                float kw = __expf(memkv[(h * DH + d) * NM + m] - km) * rsm;
                s += kw * memkv[512 + (h * DH + e) * NM + m];
            }
        }
        ctxp[(size_t)part * 131072 + (size_t)bh * 1024 + o] = s;
    }
}

// ---------------- fold ctx into out-proj weight, once per batch:
// W2[b][oc][h*32+d] = sum_e wout[oc][h*32+e] * ctx_b[h][d][e]   (bf16)
__global__ __launch_bounds__(256) void k_w2(const float* __restrict__ ctxp,
        const ushort* __restrict__ woutt, ushort* __restrict__ W2) {
    __shared__ ushort ctxb[4 * 32 * 40];   // [h][d][e], pad 40 (80B rows, 16B-aligned)
    int tid = threadIdx.x, b = blockIdx.x;
    int wid = tid >> 6;
    int l15 = tid & 15, quad = (tid >> 4) & 3;
    // sum the 8 n-partials -> bf16 LDS (mem-kv already folded in at part 0)
    #pragma unroll
    for (int j = 0; j < 16; ++j) {
        int idx = tid + j * 256;            // 0..4095 = h*1024 + d*32 + e
        float s = 0.f;
        #pragma unroll
        for (int p = 0; p < NPART; ++p)
            s += ctxp[(size_t)p * 131072 + (size_t)b * 4096 + idx];
        int h = idx >> 10, d = (idx >> 5) & 31, e = idx & 31;
        ctxb[(h * 32 + d) * 40 + e] = f2bf(s);
    }
    __syncthreads();
    // per wave: 64 oc rows; per head: one K=32 MFMA step (M=64, N=32)
    #pragma unroll
    for (int h = 0; h < 4; ++h) {
        f32x4 acc[4][2];
        #pragma unroll
        for (int i = 0; i < 4; ++i)
            #pragma unroll
            for (int j = 0; j < 2; ++j) acc[i][j] = (f32x4){0.f, 0.f, 0.f, 0.f};
        bf16x8 af[4], bfr[2];
        #pragma unroll
        for (int mt = 0; mt < 4; ++mt)
            af[mt] = *(const bf16x8*)&woutt[(size_t)(wid * 64 + mt * 16 + l15) * HID
                                            + h * DH + quad * 8];
        #pragma unroll
        for (int nt = 0; nt < 2; ++nt)
            bfr[nt] = *(const bf16x8*)&ctxb[(h * 32 + nt * 16 + l15) * 40 + quad * 8];
        #pragma unroll
        for (int mt = 0; mt < 4; ++mt)
            #pragma unroll
            for (int nt = 0; nt < 2; ++nt)
                acc[mt][nt] = __builtin_amdgcn_mfma_f32_16x16x32_bf16(
                                  af[mt], bfr[nt], acc[mt][nt], 0, 0, 0);
        #pragma unroll
        for (int mt = 0; mt < 4; ++mt)
            #pragma unroll
            for (int nt = 0; nt < 2; ++nt)
                #pragma unroll
                for (int r = 0; r < 4; ++r) {
                    int oc = wid * 64 + mt * 16 + quad * 4 + r;
                    int d  = nt * 16 + l15;
                    W2[((size_t)b * CC + oc) * HID + h * DH + d] = f2bf(acc[mt][nt][r]);
                }
    }
}

// ---------------- final: q-softmax + single GEMM (W2_b @ softq) + bias + rms*g2
__global__ __launch_bounds__(256) void k_final(const ushort* __restrict__ qkv,
        const ushort* __restrict__ W2, const float* __restrict__ bout,
        const float* __restrict__ g2, float* __restrict__ y) {
    __shared__ __align__(16) ushort sq[64 * 136];   // [pix][hid] softmaxed q, bf16
    __shared__ __align__(16) ushort Ws[256 * 32];   // staged W2 K-tile
    __shared__ float red[64 * 17];
    __shared__ float invs[64];
    __shared__ float bl[256];
    __shared__ float gl[256];
    int tid = threadIdx.x;
    int b = blockIdx.y;
    int hwb = blockIdx.x * 64;
    int lane = tid & 63, wid = tid >> 6;
    int l15 = tid & 15, quad = (tid >> 4) & 3;
    bl[tid] = bout[tid];
    gl[tid] = g2[tid];

    // ---- softmax over d per (h=wid, pix=lane); write sq[pix][hid] bf16
    {
        const ushort* qp = qkv + ((size_t)b * OC3 + wid * DH) * HW + hwb + lane;
        float vd[32];
        float m = -1e30f;
        #pragma unroll
        for (int d = 0; d < 32; ++d) {
            float v = bf2f(qp[(size_t)d * HW]);   // 64 lanes contiguous per row
            vd[d] = v; m = fmaxf(m, v);
        }
        float s = 0.f;
        #pragma unroll
        for (int d = 0; d < 32; ++d) { float e = __expf(vd[d] - m); vd[d] = e; s += e; }
        float r_ = SCALE / s;
        #pragma unroll
        for (int q8 = 0; q8 < 4; ++q8) {
            uint4 pk; ushort* o8 = (ushort*)&pk;
            #pragma unroll
            for (int i = 0; i < 8; ++i) o8[i] = f2bf(vd[q8 * 8 + i] * r_);
            *(uint4*)&sq[lane * 136 + wid * DH + q8 * 8] = pk;
        }
    }

    // ---- GEMM: y0[256 oc][64 pix] = W2_b[256][128] @ sq^T, K=128 in 4 steps
    f32x4 acc[4][4];
    #pragma unroll
    for (int i = 0; i < 4; ++i)
        #pragma unroll
        for (int j = 0; j < 4; ++j) acc[i][j] = (f32x4){0.f, 0.f, 0.f, 0.f};
    int rsub = lane >> 2, csub = (lane & 3) * 8;
    const ushort* W2b = W2 + (size_t)b * CC * HID;
    for (int k0 = 0; k0 < HID; k0 += 32) {
        __syncthreads();    // 1st iter: also guards sq writes
        #pragma unroll
        for (int q = 0; q < 4; ++q) {
            int rw = wid * 64 + q * 16;
            g2l16(W2b + (size_t)(rw + rsub) * HID + k0 + csub, &Ws[rw * 32]);
        }
        __syncthreads();
        bf16x8 af[4], bfr[4];
        #pragma unroll
        for (int mt = 0; mt < 4; ++mt)
            af[mt] = *(const bf16x8*)&Ws[(wid * 64 + mt * 16 + l15) * 32 + quad * 8];
        #pragma unroll
        for (int nt = 0; nt < 4; ++nt)
            bfr[nt] = *(const bf16x8*)&sq[(nt * 16 + l15) * 136 + k0 + quad * 8];
        #pragma unroll
        for (int mt = 0; mt < 4; ++mt)
            #pragma unroll
            for (int nt = 0; nt < 4; ++nt)
                acc[mt][nt] = __builtin_amdgcn_mfma_f32_16x16x32_bf16(
                                  af[mt], bfr[nt], acc[mt][nt], 0, 0, 0);
    }

    // ---- epilogue: bias, rms-norm over 256 oc, *g2*16
    float part[4] = {0.f, 0.f, 0.f, 0.f};
    #pragma unroll
    for (int mt = 0; mt < 4; ++mt)
        #pragma unroll
        for (int r = 0; r < 4; ++r) {
            int oc = wid * 64 + mt * 16 + quad * 4 + r;
            float bo = bl[oc];
            #pragma unroll
            for (int nt = 0; nt < 4; ++nt) {
                float v = acc[mt][nt][r] + bo;
                acc[mt][nt][r] = v;
                part[nt] += v * v;
            }
        }
    __syncthreads();
    #pragma unroll
    for (int nt = 0; nt < 4; ++nt)
        red[(nt * 16 + l15) * 17 + wid * 4 + quad] = part[nt];
    __syncthreads();
    if (tid < 64) {
        float s = 0.f;
        #pragma unroll
        for (int g = 0; g < 16; ++g) s += red[tid * 17 + g];
        invs[tid] = 1.0f / fmaxf(sqrtf(s), 1e-12f);
    }
    __syncthreads();
    #pragma unroll
    for (int mt = 0; mt < 4; ++mt)
        #pragma unroll
        for (int nt = 0; nt < 4; ++nt) {
            int pix = nt * 16 + l15;
            float iv = invs[pix];
            #pragma unroll
            for (int r = 0; r < 4; ++r) {
                int oc = wid * 64 + mt * 16 + quad * 4 + r;
                y[((size_t)(b * CC + oc)) * HW + hwb + pix] = acc[mt][nt][r] * iv * gl[oc] * 16.0f;
            }
        }
}

extern "C" void kernel_launch(void* const* d_in, const int* in_sizes, int n_in,
                              void* d_out, int out_size, void* d_ws, size_t ws_size,
                              hipStream_t stream) {
    const float* x     = (const float*)d_in[0];
    const float* g1    = (const float*)d_in[1];
    const float* memkv = (const float*)d_in[2];
    const float* wqkv  = (const float*)d_in[3];
    const float* wout  = (const float*)d_in[4];
    const float* bout  = (const float*)d_in[5];
    const float* g2    = (const float*)d_in[6];
    float* y = (float*)d_out;

    char* w = (char*)d_ws;
    ushort* wq2t  = (ushort*)w;  w += (size_t)OC3 * CC * 2;
    ushort* woutt = (ushort*)w;  w += (size_t)CC * HID * 2;
    float*  kmaxb = (float*)w;   w += 4096 * 4;
    float*  rsumb = (float*)w;   w += 4096 * 4;
    float*  ctxp  = (float*)w;   w += (size_t)NPART * 131072 * 4;  // 4 MB
    ushort* W2    = (ushort*)w;  w += (size_t)32 * CC * HID * 2;   // 2 MB
    ushort* xnT   = (ushort*)w;  w += (size_t)32 * HW * CC * 2;    // 67 MB
    ushort* qkv   = (ushort*)w;  w += (size_t)32 * OC3 * HW * 2;   // 100 MB

    k_prep  <<<dim3(384),       dim3(256), 0, stream>>>(wqkv, g1, wout, wq2t, woutt);
    k_xn    <<<dim3(4096),      dim3(256), 0, stream>>>(x, xnT);
    k_qkv   <<<dim3(3, 32, 32), dim3(256), 0, stream>>>(wq2t, xnT, qkv);
    k_ksoft <<<dim3(1024),      dim3(256), 0, stream>>>(qkv, memkv, kmaxb, rsumb);
    k_ctx   <<<dim3(128, 8),    dim3(256), 0, stream>>>(qkv, memkv, kmaxb, rsumb, ctxp);
    k_w2    <<<dim3(32),        dim3(256), 0, stream>>>(ctxp, woutt, W2);
    k_final <<<dim3(64, 32),    dim3(256), 0, stream>>>(qkv, W2, bout, g2, y);
}

// Round 4
// 358.237 us; speedup vs baseline: 1.1787x; 1.0296x over previous
//
#include <hip/hip_runtime.h>
#include <math.h>

#define CC   256
#define HW   4096
#define OC3  384
#define HID  128
#define DH   32
#define NM   4
#define NPART 8
#define SCALE 0.17677669529663688f  // 32^-0.5

typedef __bf16 bf16x8 __attribute__((ext_vector_type(8)));
typedef float  f32x4  __attribute__((ext_vector_type(4)));

__device__ __forceinline__ ushort f2bf(float x) {
    union { float f; unsigned u; } v; v.f = x;
    unsigned r = v.u + 0x7fffu + ((v.u >> 16) & 1u);   // RNE
    return (ushort)(r >> 16);
}
__device__ __forceinline__ float bf2f(ushort b) {
    union { unsigned u; float f; } v; v.u = ((unsigned)b) << 16; return v.f;
}
__device__ __forceinline__ void g2l16(const void* g, void* l) {
    __builtin_amdgcn_global_load_lds(
        (const __attribute__((address_space(1))) void*)g,
        (__attribute__((address_space(3))) void*)l, 16, 0, 0);
}

// ---------------- prep: wq2t[o][c] = wqkv[o][c]*g1[c]*16 (bf16); woutt = bf16(wout)
__global__ void k_prep(const float* __restrict__ wqkv, const float* __restrict__ g1,
                       const float* __restrict__ wout,
                       ushort* __restrict__ wq2t, ushort* __restrict__ woutt) {
    int o = blockIdx.x, t = threadIdx.x;
    wq2t[(size_t)o * CC + t] = f2bf(wqkv[(size_t)o * CC + t] * g1[t] * 16.0f);
    if (o < CC && t < HID) woutt[(size_t)o * HID + t] = f2bf(wout[(size_t)o * HID + t]);
}

// ---------------- qkv MFMA GEMM, v3: consumes RAW x (fp32, [C][HW]).
// RMS-norm folded into the epilogue: qkv[o][p] = inv[p] * sum_c W'[o][c] x[c][p],
// inv[p] = 1/max(||x[:,p]||,eps). Per K-step the B-tile is transposed in-LDS
// (xt fp32 [32c][132pix] -> Bs bf16 [128pix][40-stride k]); per-pixel sum(x^2)
// accumulates as a free byproduct of the transpose pass (threads t,t+128 pair
// covers all 32 c per pixel per step). Eliminates the former k_xn kernel and
// its 134 MB xnT round-trip.
__global__ __launch_bounds__(256) void k_qkv(const ushort* __restrict__ wq2t,
        const float* __restrict__ x, ushort* __restrict__ qkv) {
    __shared__ __align__(16) ushort As[128 * 32];   // A tile [oc][32k]
    __shared__ __align__(16) ushort Bs[128 * 40];   // B tile [pix][k], stride 40
    __shared__ __align__(16) float  xt[32 * 132];   // fp32 x tile [c][pix], stride 132
    __shared__ float nrm[256];
    __shared__ float invp[128];
    int tid = threadIdx.x;
    int lin = blockIdx.x + 3 * (blockIdx.y + 32 * blockIdx.z);   // 0..3071
    int swz = (lin & 7) * 384 + (lin >> 3);                      // XCD-bijective
    int m0 = (swz % 3) * 128;
    int t_ = swz / 3;                                            // 0..1023
    int p0 = (t_ & 31) * 128;
    int b  = t_ >> 5;
    int lane = tid & 63, wid = tid >> 6;
    int l15 = tid & 15, quad = (tid >> 4) & 3;
    int wm = wid >> 1, wn = wid & 1;
    int rsub = lane >> 2, csub = (lane & 3) * 8;
    int cb = tid >> 5;              // 0..7: c row group for fp32 stage
    int p4 = (tid & 31) * 4;        // 4-pixel chunk
    int tpix = tid & 127;           // transpose: pixel owned by this thread
    int tc8  = (tid >> 7) * 8;      // 0 or 8 (+16 on round 1)
    const ushort* Ab = wq2t + (size_t)m0 * CC;
    const float*  xb = x + ((size_t)b * CC) * HW + p0;
    float psum = 0.f;
    f32x4 acc[4][4];
    #pragma unroll
    for (int i = 0; i < 4; ++i)
        #pragma unroll
        for (int j = 0; j < 4; ++j) acc[i][j] = (f32x4){0.f, 0.f, 0.f, 0.f};
    for (int k0 = 0; k0 < CC; k0 += 32) {
        __syncthreads();
        #pragma unroll
        for (int q = 0; q < 2; ++q) {
            int rw = wid * 32 + q * 16;
            g2l16(Ab + (size_t)(rw + rsub) * CC + k0 + csub, &As[rw * 32]);
        }
        #pragma unroll
        for (int rr = 0; rr < 4; ++rr) {
            int c = rr * 8 + cb;
            float4 v = *(const float4*)&xb[(size_t)(k0 + c) * HW + p4];
            *(float4*)&xt[c * 132 + p4] = v;
        }
        __syncthreads();
        #pragma unroll
        for (int rr = 0; rr < 2; ++rr) {
            int c8 = tc8 + rr * 16;
            uint4 pk; ushort* o8 = (ushort*)&pk;
            #pragma unroll
            for (int i = 0; i < 8; ++i) {
                float v = xt[(c8 + i) * 132 + tpix];
                psum += v * v;
                o8[i] = f2bf(v);
            }
            *(uint4*)&Bs[tpix * 40 + c8] = pk;
        }
        __syncthreads();
        bf16x8 af[4], bfr[4];
        #pragma unroll
        for (int mt = 0; mt < 4; ++mt)
            af[mt] = *(const bf16x8*)&As[(wm * 64 + mt * 16 + l15) * 32 + quad * 8];
        #pragma unroll
        for (int nt = 0; nt < 4; ++nt)
            bfr[nt] = *(const bf16x8*)&Bs[(wn * 64 + nt * 16 + l15) * 40 + quad * 8];
        #pragma unroll
        for (int mt = 0; mt < 4; ++mt)
            #pragma unroll
            for (int nt = 0; nt < 4; ++nt)
                acc[mt][nt] = __builtin_amdgcn_mfma_f32_16x16x32_bf16(
                                  af[mt], bfr[nt], acc[mt][nt], 0, 0, 0);
    }
    // per-pixel inv norm: threads t and t+128 hold the two halves of sum(x^2)
    nrm[tid] = psum;
    __syncthreads();
    if (tid < 128) {
        float s = nrm[tid] + nrm[tid + 128];
        invp[tid] = 1.0f / fmaxf(sqrtf(s), 1e-12f);
    }
    __syncthreads();
    #pragma unroll
    for (int mt = 0; mt < 4; ++mt) {
        int o = m0 + wm * 64 + mt * 16 + quad * 4;
        #pragma unroll
        for (int nt = 0; nt < 4; ++nt) {
            int pixl = wn * 64 + nt * 16 + l15;
            float iv = invp[pixl];
            ushort* dst = qkv + ((size_t)(b * OC3 + o)) * HW + p0 + pixl;
            #pragma unroll
            for (int r = 0; r < 4; ++r) dst[(size_t)r * HW] = f2bf(acc[mt][nt][r] * iv);
        }
    }
}

// ---------------- k-softmax stats over bf16 k rows (uint4 loads)
__global__ void k_ksoft(const ushort* __restrict__ qkv, const float* __restrict__ memkv,
                        float* __restrict__ kmaxb, float* __restrict__ rsumb) {
    int row = blockIdx.x * 4 + (threadIdx.x >> 6);
    int lane = threadIdx.x & 63;
    int b = row >> 7, hd = row & 127;
    const ushort* kp = qkv + ((size_t)(b * OC3 + HID + hd)) * HW;
    float m = -1e30f;
    #pragma unroll
    for (int i0 = 0; i0 < HW; i0 += 512) {
        uint4 pk = *(const uint4*)&kp[i0 + lane * 8];
        const ushort* e = (const ushort*)&pk;
        #pragma unroll
        for (int j = 0; j < 8; ++j) m = fmaxf(m, bf2f(e[j]));
    }
    #pragma unroll
    for (int s = 1; s < 64; s <<= 1) m = fmaxf(m, __shfl_xor(m, s));
    const float* mk = memkv + hd * NM;
    #pragma unroll
    for (int j = 0; j < NM; ++j) m = fmaxf(m, mk[j]);
    float s = 0.f;
    #pragma unroll
    for (int i0 = 0; i0 < HW; i0 += 512) {
        uint4 pk = *(const uint4*)&kp[i0 + lane * 8];
        const ushort* e = (const ushort*)&pk;
        #pragma unroll
        for (int j = 0; j < 8; ++j) s += __expf(bf2f(e[j]) - m);
    }
    #pragma unroll
    for (int t = 1; t < 64; t <<= 1) s += __shfl_xor(s, t);
    #pragma unroll
    for (int j = 0; j < NM; ++j) s += __expf(mk[j] - m);
    if (lane == 0) { kmaxb[row] = m; rsumb[row] = 1.0f / s; }
}

// ---------------- context partials: ctxp[part][bh][d*32+e], n split 8 ways
__global__ __launch_bounds__(256) void k_ctx(const ushort* __restrict__ qkv,
        const float* __restrict__ memkv, const float* __restrict__ kmaxb,
        const float* __restrict__ rsumb, float* __restrict__ ctxp) {
    __shared__ float kl[DH][65];
    __shared__ float vl[DH][65];
    __shared__ float red[256 * 33];
    int tid = threadIdx.x;
    int bh = blockIdx.x;            // 0..127
    int part = blockIdx.y;          // 0..7
    int b = bh >> 2, h = bh & 3;
    int lr = tid >> 3;              // 0..31: k/v row this thread stages
    int nn8 = (tid & 7) * 8;        // 8-col chunk
    const ushort* kp = qkv + ((size_t)(b * OC3 + HID + h * DH) + lr) * HW + part * 512 + nn8;
    const ushort* vp = qkv + ((size_t)(b * OC3 + 2 * HID + h * DH) + lr) * HW + part * 512 + nn8;
    int rowbase = bh * DH;
    float kmr = kmaxb[rowbase + lr], rsr = rsumb[rowbase + lr];
    int slot = tid & 31, nng = tid >> 5;
    int d0 = (slot >> 2) * 4, e0 = (slot & 3) * 8;
    float acc[4][8];
    #pragma unroll
    for (int i = 0; i < 4; ++i)
        #pragma unroll
        for (int j = 0; j < 8; ++j) acc[i][j] = 0.f;
    for (int n0 = 0; n0 < 512; n0 += 64) {
        __syncthreads();
        uint4 kv4 = *(const uint4*)&kp[n0];
        uint4 vv4 = *(const uint4*)&vp[n0];
        const ushort* ke = (const ushort*)&kv4;
        const ushort* ve = (const ushort*)&vv4;
        #pragma unroll
        for (int j = 0; j < 8; ++j) {
            kl[lr][nn8 + j] = __expf(bf2f(ke[j]) - kmr) * rsr;
            vl[lr][nn8 + j] = bf2f(ve[j]);
        }
        __syncthreads();
        #pragma unroll 2
        for (int t = 0; t < 8; ++t) {
            int nn = nng * 8 + t;
            float kv[4], vv[8];
            #pragma unroll
            for (int i = 0; i < 4; ++i) kv[i] = kl[d0 + i][nn];
            #pragma unroll
            for (int j = 0; j < 8; ++j) vv[j] = vl[e0 + j][nn];
            #pragma unroll
            for (int i = 0; i < 4; ++i)
                #pragma unroll
                for (int j = 0; j < 8; ++j) acc[i][j] += kv[i] * vv[j];
        }
    }
    __syncthreads();
    #pragma unroll
    for (int i = 0; i < 4; ++i)
        #pragma unroll
        for (int j = 0; j < 8; ++j) red[tid * 33 + i * 8 + j] = acc[i][j];
    __syncthreads();
    #pragma unroll
    for (int q = 0; q < 4; ++q) {
        int o = tid * 4 + q;
        int d = o >> 5, e = o & 31;
        int sl = (d >> 2) * 4 + (e >> 3);
        int k = (d & 3) * 8 + (e & 7);
        float s = 0.f;
        #pragma unroll
        for (int g = 0; g < 8; ++g) s += red[(g * 32 + sl) * 33 + k];
        if (part == 0) {   // memory-kv contribution added once
            float km = kmaxb[rowbase + d], rsm = rsumb[rowbase + d];
            #pragma unroll
            for (int m = 0; m < NM; ++m) {
                float kw = __expf(memkv[(h * DH + d) * NM + m] - km) * rsm;
                s += kw * memkv[512 + (h * DH + e) * NM + m];
            }
        }
        ctxp[(size_t)part * 131072 + (size_t)bh * 1024 + o] = s;
    }
}

// ---------------- fold ctx into out-proj weight, once per batch:
// W2[b][oc][h*32+d] = sum_e wout[oc][h*32+e] * ctx_b[h][d][e]   (bf16)
__global__ __launch_bounds__(256) void k_w2(const float* __restrict__ ctxp,
        const ushort* __restrict__ woutt, ushort* __restrict__ W2) {
    __shared__ ushort ctxb[4 * 32 * 40];   // [h][d][e], pad 40 (80B rows, 16B-aligned)
    int tid = threadIdx.x, b = blockIdx.x;
    int wid = tid >> 6;
    int l15 = tid & 15, quad = (tid >> 4) & 3;
    // sum the 8 n-partials -> bf16 LDS (mem-kv already folded in at part 0)
    #pragma unroll
    for (int j = 0; j < 16; ++j) {
        int idx = tid + j * 256;            // 0..4095 = h*1024 + d*32 + e
        float s = 0.f;
        #pragma unroll
        for (int p = 0; p < NPART; ++p)
            s += ctxp[(size_t)p * 131072 + (size_t)b * 4096 + idx];
        int h = idx >> 10, d = (idx >> 5) & 31, e = idx & 31;
        ctxb[(h * 32 + d) * 40 + e] = f2bf(s);
    }
    __syncthreads();
    // per wave: 64 oc rows; per head: one K=32 MFMA step (M=64, N=32)
    #pragma unroll
    for (int h = 0; h < 4; ++h) {
        f32x4 acc[4][2];
        #pragma unroll
        for (int i = 0; i < 4; ++i)
            #pragma unroll
            for (int j = 0; j < 2; ++j) acc[i][j] = (f32x4){0.f, 0.f, 0.f, 0.f};
        bf16x8 af[4], bfr[2];
        #pragma unroll
        for (int mt = 0; mt < 4; ++mt)
            af[mt] = *(const bf16x8*)&woutt[(size_t)(wid * 64 + mt * 16 + l15) * HID
                                            + h * DH + quad * 8];
        #pragma unroll
        for (int nt = 0; nt < 2; ++nt)
            bfr[nt] = *(const bf16x8*)&ctxb[(h * 32 + nt * 16 + l15) * 40 + quad * 8];
        #pragma unroll
        for (int mt = 0; mt < 4; ++mt)
            #pragma unroll
            for (int nt = 0; nt < 2; ++nt)
                acc[mt][nt] = __builtin_amdgcn_mfma_f32_16x16x32_bf16(
                                  af[mt], bfr[nt], acc[mt][nt], 0, 0, 0);
        #pragma unroll
        for (int mt = 0; mt < 4; ++mt)
            #pragma unroll
            for (int nt = 0; nt < 2; ++nt)
                #pragma unroll
                for (int r = 0; r < 4; ++r) {
                    int oc = wid * 64 + mt * 16 + quad * 4 + r;
                    int d  = nt * 16 + l15;
                    W2[((size_t)b * CC + oc) * HID + h * DH + d] = f2bf(acc[mt][nt][r]);
                }
    }
}

// ---------------- final: q-softmax + single GEMM (W2_b @ softq) + bias + rms*g2
__global__ __launch_bounds__(256) void k_final(const ushort* __restrict__ qkv,
        const ushort* __restrict__ W2, const float* __restrict__ bout,
        const float* __restrict__ g2, float* __restrict__ y) {
    __shared__ __align__(16) ushort sq[64 * 136];   // [pix][hid] softmaxed q, bf16
    __shared__ __align__(16) ushort Ws[256 * 32];   // staged W2 K-tile
    __shared__ float red[64 * 17];
    __shared__ float invs[64];
    __shared__ float bl[256];
    __shared__ float gl[256];
    int tid = threadIdx.x;
    int b = blockIdx.y;
    int hwb = blockIdx.x * 64;
    int lane = tid & 63, wid = tid >> 6;
    int l15 = tid & 15, quad = (tid >> 4) & 3;
    bl[tid] = bout[tid];
    gl[tid] = g2[tid];

    // ---- softmax over d per (h=wid, pix=lane); write sq[pix][hid] bf16
    {
        const ushort* qp = qkv + ((size_t)b * OC3 + wid * DH) * HW + hwb + lane;
        float vd[32];
        float m = -1e30f;
        #pragma unroll
        for (int d = 0; d < 32; ++d) {
            float v = bf2f(qp[(size_t)d * HW]);   // 64 lanes contiguous per row
            vd[d] = v; m = fmaxf(m, v);
        }
        float s = 0.f;
        #pragma unroll
        for (int d = 0; d < 32; ++d) { float e = __expf(vd[d] - m); vd[d] = e; s += e; }
        float r_ = SCALE / s;
        #pragma unroll
        for (int q8 = 0; q8 < 4; ++q8) {
            uint4 pk; ushort* o8 = (ushort*)&pk;
            #pragma unroll
            for (int i = 0; i < 8; ++i) o8[i] = f2bf(vd[q8 * 8 + i] * r_);
            *(uint4*)&sq[lane * 136 + wid * DH + q8 * 8] = pk;
        }
    }

    // ---- GEMM: y0[256 oc][64 pix] = W2_b[256][128] @ sq^T, K=128 in 4 steps
    f32x4 acc[4][4];
    #pragma unroll
    for (int i = 0; i < 4; ++i)
        #pragma unroll
        for (int j = 0; j < 4; ++j) acc[i][j] = (f32x4){0.f, 0.f, 0.f, 0.f};
    int rsub = lane >> 2, csub = (lane & 3) * 8;
    const ushort* W2b = W2 + (size_t)b * CC * HID;
    for (int k0 = 0; k0 < HID; k0 += 32) {
        __syncthreads();    // 1st iter: also guards sq writes
        #pragma unroll
        for (int q = 0; q < 4; ++q) {
            int rw = wid * 64 + q * 16;
            g2l16(W2b + (size_t)(rw + rsub) * HID + k0 + csub, &Ws[rw * 32]);
        }
        __syncthreads();
        bf16x8 af[4], bfr[4];
        #pragma unroll
        for (int mt = 0; mt < 4; ++mt)
            af[mt] = *(const bf16x8*)&Ws[(wid * 64 + mt * 16 + l15) * 32 + quad * 8];
        #pragma unroll
        for (int nt = 0; nt < 4; ++nt)
            bfr[nt] = *(const bf16x8*)&sq[(nt * 16 + l15) * 136 + k0 + quad * 8];
        #pragma unroll
        for (int mt = 0; mt < 4; ++mt)
            #pragma unroll
            for (int nt = 0; nt < 4; ++nt)
                acc[mt][nt] = __builtin_amdgcn_mfma_f32_16x16x32_bf16(
                                  af[mt], bfr[nt], acc[mt][nt], 0, 0, 0);
    }

    // ---- epilogue: bias, rms-norm over 256 oc, *g2*16
    float part[4] = {0.f, 0.f, 0.f, 0.f};
    #pragma unroll
    for (int mt = 0; mt < 4; ++mt)
        #pragma unroll
        for (int r = 0; r < 4; ++r) {
            int oc = wid * 64 + mt * 16 + quad * 4 + r;
            float bo = bl[oc];
            #pragma unroll
            for (int nt = 0; nt < 4; ++nt) {
                float v = acc[mt][nt][r] + bo;
                acc[mt][nt][r] = v;
                part[nt] += v * v;
            }
        }
    __syncthreads();
    #pragma unroll
    for (int nt = 0; nt < 4; ++nt)
        red[(nt * 16 + l15) * 17 + wid * 4 + quad] = part[nt];
    __syncthreads();
    if (tid < 64) {
        float s = 0.f;
        #pragma unroll
        for (int g = 0; g < 16; ++g) s += red[tid * 17 + g];
        invs[tid] = 1.0f / fmaxf(sqrtf(s), 1e-12f);
    }
    __syncthreads();
    #pragma unroll
    for (int mt = 0; mt < 4; ++mt)
        #pragma unroll
        for (int nt = 0; nt < 4; ++nt) {
            int pix = nt * 16 + l15;
            float iv = invs[pix];
            #pragma unroll
            for (int r = 0; r < 4; ++r) {
                int oc = wid * 64 + mt * 16 + quad * 4 + r;
                y[((size_t)(b * CC + oc)) * HW + hwb + pix] = acc[mt][nt][r] * iv * gl[oc] * 16.0f;
            }
        }
}

extern "C" void kernel_launch(void* const* d_in, const int* in_sizes, int n_in,
                              void* d_out, int out_size, void* d_ws, size_t ws_size,
                              hipStream_t stream) {
    const float* x     = (const float*)d_in[0];
    const float* g1    = (const float*)d_in[1];
    const float* memkv = (const float*)d_in[2];
    const float* wqkv  = (const float*)d_in[3];
    const float* wout  = (const float*)d_in[4];
    const float* bout  = (const float*)d_in[5];
    const float* g2    = (const float*)d_in[6];
    float* y = (float*)d_out;

    char* w = (char*)d_ws;
    ushort* wq2t  = (ushort*)w;  w += (size_t)OC3 * CC * 2;
    ushort* woutt = (ushort*)w;  w += (size_t)CC * HID * 2;
    float*  kmaxb = (float*)w;   w += 4096 * 4;
    float*  rsumb = (float*)w;   w += 4096 * 4;
    float*  ctxp  = (float*)w;   w += (size_t)NPART * 131072 * 4;  // 4 MB
    ushort* W2    = (ushort*)w;  w += (size_t)32 * CC * HID * 2;   // 2 MB
    ushort* qkv   = (ushort*)w;  w += (size_t)32 * OC3 * HW * 2;   // 100 MB

    k_prep  <<<dim3(384),       dim3(256), 0, stream>>>(wqkv, g1, wout, wq2t, woutt);
    k_qkv   <<<dim3(3, 32, 32), dim3(256), 0, stream>>>(wq2t, x, qkv);
    k_ksoft <<<dim3(1024),      dim3(256), 0, stream>>>(qkv, memkv, kmaxb, rsumb);
    k_ctx   <<<dim3(128, 8),    dim3(256), 0, stream>>>(qkv, memkv, kmaxb, rsumb, ctxp);
    k_w2    <<<dim3(32),        dim3(256), 0, stream>>>(ctxp, woutt, W2);
    k_final <<<dim3(64, 32),    dim3(256), 0, stream>>>(qkv, W2, bout, g2, y);
}